// Round 15
// baseline (939.986 us; speedup 1.0000x reference)
//
#include <hip/hip_runtime.h>
#include <hip/hip_bf16.h>

// GCN layer: out = A_hat @ (x @ W) + bias,  A_hat = D^-1/2 (A+I) D^-1/2.
// N=50000, E=600000, IN=128, OUT=64.
//
// Round-13 profile: gemm 45us (2/3 of total), latency-bound (VALUBusy 17%,
// VGPR=52 -> no load ILP). Fix: explicit 4-deep prefetch ring on x loads.
// (Round 14 failed on a token-pasting bug: 0.x is one pp-token. Macros now
// take full variable names - no ## at all.)
//
// Pipeline (3 kernels):
//   1) zero_cnt (tiny)
//   2) MEGA role-split: blocks [0,782) gemm tiles (W in LDS, x broadcast,
//      4-deep prefetch ring); blocks [782,1024) fill_bucket grid-stride.
//   3) gather (round-10 best): wave/node, tiered 8/4 loads, block=128.
//
// NOTE: "fillBufferAligned 256MB" rows = HARNESS d_ws poisoning, not timed.
// NOTE: coop launch silently fails (r9); NT hints +13us (r8); launch ~5us.
//
// ws: [cnt: N int][y: N*64 ushort(bf16)][bucket: N*64 int]

#define IN_CH 128
#define OUT_CH 64
#define CAP 64
#define NPB 64
#define GEMM_BLOCKS 782   // ceil(50000/64)
#define BUCKET_BLOCKS 242
#define TOTAL_BLOCKS (GEMM_BLOCKS + BUCKET_BLOCKS)

__global__ void zero_cnt_kernel(int* __restrict__ cnt, int n) {
    int i = blockIdx.x * blockDim.x + threadIdx.x;
    if (i < n) cnt[i] = 0;
}

__device__ __forceinline__ unsigned short f2bf(float f) {
    unsigned int u = __float_as_uint(f);
    unsigned int r = (u + 0x7fffu + ((u >> 16) & 1u)) >> 16;  // RTN-even
    return (unsigned short)r;
}

#define FMA4(A, xs, Wv) \
    A.x = fmaf(xs, Wv.x, A.x); A.y = fmaf(xs, Wv.y, A.y); \
    A.z = fmaf(xs, Wv.z, A.z); A.w = fmaf(xs, Wv.w, A.w);

// load one X set (4 node rows, k4-th float4 each)
#define LOADSET(V0, V1, V2, V3, K) \
    V0 = xr0[K]; V1 = xr1[K]; V2 = xr2[K]; V3 = xr3[K];

// consume one X set against the W column-block for k4=K
#define STEPW(V0, V1, V2, V3, K) { \
    const float4 W0 = *reinterpret_cast<const float4*>(&wl[((K) * 4 + 0) * OUT_CH + c0]); \
    const float4 W1 = *reinterpret_cast<const float4*>(&wl[((K) * 4 + 1) * OUT_CH + c0]); \
    const float4 W2 = *reinterpret_cast<const float4*>(&wl[((K) * 4 + 2) * OUT_CH + c0]); \
    const float4 W3 = *reinterpret_cast<const float4*>(&wl[((K) * 4 + 3) * OUT_CH + c0]); \
    FMA4(A0, V0.x, W0) FMA4(A0, V0.y, W1) FMA4(A0, V0.z, W2) FMA4(A0, V0.w, W3) \
    FMA4(A1, V1.x, W0) FMA4(A1, V1.y, W1) FMA4(A1, V1.z, W2) FMA4(A1, V1.w, W3) \
    FMA4(A2, V2.x, W0) FMA4(A2, V2.y, W1) FMA4(A2, V2.z, W2) FMA4(A2, V2.w, W3) \
    FMA4(A3, V3.x, W0) FMA4(A3, V3.y, W1) FMA4(A3, V3.z, W2) FMA4(A3, V3.w, W3) \
}

// one pipeline group: consume k4=4g..4g+3 while loading k4=4g+4..4g+7
#define GROUP(g) \
    STEPW(XA0, XA1, XA2, XA3, 4 * (g) + 0) LOADSET(XA0, XA1, XA2, XA3, 4 * (g) + 4) \
    STEPW(XB0, XB1, XB2, XB3, 4 * (g) + 1) LOADSET(XB0, XB1, XB2, XB3, 4 * (g) + 5) \
    STEPW(XC0, XC1, XC2, XC3, 4 * (g) + 2) LOADSET(XC0, XC1, XC2, XC3, 4 * (g) + 6) \
    STEPW(XD0, XD1, XD2, XD3, 4 * (g) + 3) LOADSET(XD0, XD1, XD2, XD3, 4 * (g) + 7)

__global__ __launch_bounds__(256, 4) void mega_kernel(const float* __restrict__ x,
                                                      const float* __restrict__ w,
                                                      const int* __restrict__ ei,
                                                      unsigned short* __restrict__ y,
                                                      int* __restrict__ cnt,
                                                      int* __restrict__ bucket,
                                                      int n, int nE) {
    __shared__ float wl[IN_CH * OUT_CH];   // 32 KB (gemm role only)
    const int t = threadIdx.x;

    if (blockIdx.x >= GEMM_BLOCKS) {
        // ---- bucket role: grid-stride over edge pairs ----
        const int nPairs = (nE + 1) / 2;
        const int stride = BUCKET_BLOCKS * 256;
        for (int p = (blockIdx.x - GEMM_BLOCKS) * 256 + t; p < nPairs; p += stride) {
            int e0 = p * 2;
            int2 s2 = reinterpret_cast<const int2*>(ei)[p];
            int2 d2 = reinterpret_cast<const int2*>(ei + nE)[p];
            int pos0 = atomicAdd(&cnt[d2.x], 1);
            if (pos0 < CAP) bucket[(size_t)d2.x * CAP + pos0] = s2.x;
            if (e0 + 1 < nE) {
                int pos1 = atomicAdd(&cnt[d2.y], 1);
                if (pos1 < CAP) bucket[(size_t)d2.y * CAP + pos1] = s2.y;
            }
        }
        return;
    }

    // ---- gemm role ----
    const int base = blockIdx.x * NPB;
    {
        const float4* w4 = reinterpret_cast<const float4*>(w);
        float4* wl4 = reinterpret_cast<float4*>(wl);
        #pragma unroll
        for (int i = 0; i < 8; ++i) wl4[t + i * 256] = w4[t + i * 256];
    }
    __syncthreads();

    const int nq = t >> 4;
    const int cq = t & 15;
    const int n0 = base + nq * 4;
    const int c0 = cq * 4;

    const float4* xr0 = reinterpret_cast<const float4*>(x + (size_t)min(n0 + 0, n - 1) * IN_CH);
    const float4* xr1 = reinterpret_cast<const float4*>(x + (size_t)min(n0 + 1, n - 1) * IN_CH);
    const float4* xr2 = reinterpret_cast<const float4*>(x + (size_t)min(n0 + 2, n - 1) * IN_CH);
    const float4* xr3 = reinterpret_cast<const float4*>(x + (size_t)min(n0 + 3, n - 1) * IN_CH);

    float4 A0 = make_float4(0.f, 0.f, 0.f, 0.f);
    float4 A1 = A0, A2 = A0, A3 = A0;

    // prefetch ring: 4 named sets (64 VGPRs), no address-taken arrays
    float4 XA0, XA1, XA2, XA3, XB0, XB1, XB2, XB3;
    float4 XC0, XC1, XC2, XC3, XD0, XD1, XD2, XD3;

    LOADSET(XA0, XA1, XA2, XA3, 0)
    LOADSET(XB0, XB1, XB2, XB3, 1)
    LOADSET(XC0, XC1, XC2, XC3, 2)
    LOADSET(XD0, XD1, XD2, XD3, 3)
    GROUP(0) GROUP(1) GROUP(2) GROUP(3) GROUP(4) GROUP(5) GROUP(6)
    STEPW(XA0, XA1, XA2, XA3, 28)
    STEPW(XB0, XB1, XB2, XB3, 29)
    STEPW(XC0, XC1, XC2, XC3, 30)
    STEPW(XD0, XD1, XD2, XD3, 31)

    #define STORE_ROW(J, A)                                                            \
        if (n0 + J < n) {                                                              \
            uint2 pk;                                                                  \
            pk.x = (unsigned int)f2bf(A.x) | ((unsigned int)f2bf(A.y) << 16);          \
            pk.y = (unsigned int)f2bf(A.z) | ((unsigned int)f2bf(A.w) << 16);          \
            *reinterpret_cast<uint2*>(&y[(size_t)(n0 + J) * OUT_CH + c0]) = pk;        \
        }
    STORE_ROW(0, A0)
    STORE_ROW(1, A1)
    STORE_ROW(2, A2)
    STORE_ROW(3, A3)
    #undef STORE_ROW
}

// Gather (round-10 best): one wave per node, block=128 (32 waves/CU).
#define EDGE_FMA(c, v) \
    ax = fmaf(c, __uint_as_float((v) << 16), ax); \
    ay = fmaf(c, __uint_as_float((v) & 0xffff0000u), ay);

__global__ __launch_bounds__(128) void gather_kernel(const int* __restrict__ cnt,
                                                     const int* __restrict__ bucket,
                                                     const unsigned short* __restrict__ y,
                                                     const float* __restrict__ bias,
                                                     float* __restrict__ out, int n) {
    const int wid  = threadIdx.x >> 6;
    const int lane = threadIdx.x & 63;
    const int nid  = blockIdx.x * 2 + wid;
    if (nid >= n) return;
    const int hw = lane >> 5;
    const int cp = lane & 31;

    int deg = cnt[nid];
    if (deg > CAP) deg = CAP;
    const float isd_d = rsqrtf((float)cnt[nid] + 1.0f);

    int   s_l  = 0;
    float cf_l = 0.f;
    if (lane < deg) {
        s_l  = bucket[(size_t)nid * CAP + lane];
        cf_l = isd_d * rsqrtf((float)cnt[s_l] + 1.0f);
    }

    float ax = 0.f, ay = 0.f;
    if (hw == 0) {
        float2 b2 = reinterpret_cast<const float2*>(bias)[cp];
        unsigned int u = reinterpret_cast<const unsigned int*>(y + (size_t)nid * OUT_CH)[cp];
        float sl = isd_d * isd_d;
        ax = fmaf(sl, __uint_as_float(u << 16), b2.x);
        ay = fmaf(sl, __uint_as_float(u & 0xffff0000u), b2.y);
    }

    for (int k = 0; k < deg; k += 16) {
        int rem = deg - k;
        if (rem > 8) {
            int s0 = __shfl(s_l, k + 0 + hw),  s1 = __shfl(s_l, k + 2 + hw);
            int s2 = __shfl(s_l, k + 4 + hw),  s3 = __shfl(s_l, k + 6 + hw);
            int s4 = __shfl(s_l, k + 8 + hw),  s5 = __shfl(s_l, k + 10 + hw);
            int s6 = __shfl(s_l, k + 12 + hw), s7 = __shfl(s_l, k + 14 + hw);
            unsigned int v0 = reinterpret_cast<const unsigned int*>(y + (size_t)s0 * OUT_CH)[cp];
            unsigned int v1 = reinterpret_cast<const unsigned int*>(y + (size_t)s1 * OUT_CH)[cp];
            unsigned int v2 = reinterpret_cast<const unsigned int*>(y + (size_t)s2 * OUT_CH)[cp];
            unsigned int v3 = reinterpret_cast<const unsigned int*>(y + (size_t)s3 * OUT_CH)[cp];
            unsigned int v4 = reinterpret_cast<const unsigned int*>(y + (size_t)s4 * OUT_CH)[cp];
            unsigned int v5 = reinterpret_cast<const unsigned int*>(y + (size_t)s5 * OUT_CH)[cp];
            unsigned int v6 = reinterpret_cast<const unsigned int*>(y + (size_t)s6 * OUT_CH)[cp];
            unsigned int v7 = reinterpret_cast<const unsigned int*>(y + (size_t)s7 * OUT_CH)[cp];
            float c0 = __shfl(cf_l, k + 0 + hw),  c1 = __shfl(cf_l, k + 2 + hw);
            float c2 = __shfl(cf_l, k + 4 + hw),  c3 = __shfl(cf_l, k + 6 + hw);
            float c4 = __shfl(cf_l, k + 8 + hw),  c5 = __shfl(cf_l, k + 10 + hw);
            float c6 = __shfl(cf_l, k + 12 + hw), c7 = __shfl(cf_l, k + 14 + hw);
            EDGE_FMA(c0, v0) EDGE_FMA(c1, v1) EDGE_FMA(c2, v2) EDGE_FMA(c3, v3)
            EDGE_FMA(c4, v4) EDGE_FMA(c5, v5) EDGE_FMA(c6, v6) EDGE_FMA(c7, v7)
        } else {
            int s0 = __shfl(s_l, k + 0 + hw), s1 = __shfl(s_l, k + 2 + hw);
            int s2 = __shfl(s_l, k + 4 + hw), s3 = __shfl(s_l, k + 6 + hw);
            unsigned int v0 = reinterpret_cast<const unsigned int*>(y + (size_t)s0 * OUT_CH)[cp];
            unsigned int v1 = reinterpret_cast<const unsigned int*>(y + (size_t)s1 * OUT_CH)[cp];
            unsigned int v2 = reinterpret_cast<const unsigned int*>(y + (size_t)s2 * OUT_CH)[cp];
            unsigned int v3 = reinterpret_cast<const unsigned int*>(y + (size_t)s3 * OUT_CH)[cp];
            float c0 = __shfl(cf_l, k + 0 + hw), c1 = __shfl(cf_l, k + 2 + hw);
            float c2 = __shfl(cf_l, k + 4 + hw), c3 = __shfl(cf_l, k + 6 + hw);
            EDGE_FMA(c0, v0) EDGE_FMA(c1, v1) EDGE_FMA(c2, v2) EDGE_FMA(c3, v3)
        }
    }

    ax += __shfl_xor(ax, 32);
    ay += __shfl_xor(ay, 32);
    if (hw == 0) {
        float2 o; o.x = ax; o.y = ay;
        reinterpret_cast<float2*>(out + (size_t)nid * OUT_CH)[cp] = o;
    }
}

extern "C" void kernel_launch(void* const* d_in, const int* in_sizes, int n_in,
                              void* d_out, int out_size, void* d_ws, size_t ws_size,
                              hipStream_t stream) {
    const float* x    = (const float*)d_in[0];
    const int*   ei   = (const int*)d_in[1];
    const float* w    = (const float*)d_in[2];
    const float* bias = (const float*)d_in[3];
    float* out = (float*)d_out;

    const int n  = in_sizes[0] / IN_CH;   // 50000
    const int nE = in_sizes[1] / 2;       // 600000

    char* p = (char*)d_ws;
    auto align256 = [](size_t v) { return (v + 255) & ~(size_t)255; };
    int*            cnt    = (int*)p;             p += align256((size_t)n * 4);
    unsigned short* y      = (unsigned short*)p;  p += align256((size_t)n * OUT_CH * 2);
    int*            bucket = (int*)p;

    zero_cnt_kernel<<<(n + 255) / 256, 256, 0, stream>>>(cnt, n);
    mega_kernel<<<TOTAL_BLOCKS, 256, 0, stream>>>(x, w, ei, y, cnt, bucket, n, nE);
    gather_kernel<<<(n + 1) / 2, 128, 0, stream>>>(cnt, bucket, y, bias, out, n);
}

// Round 16
// 470.453 us; speedup vs baseline: 1.9980x; 1.9980x over previous
//
#include <hip/hip_runtime.h>
#include <hip/hip_bf16.h>

// GCN layer: out = A_hat @ (x @ W) + bias,  A_hat = D^-1/2 (A+I) D^-1/2.
// N=50000, E=600000, IN=128, OUT=64.
//
// Round-13 profile: gemm 45us (2/3 of total), latency-bound (VALUBusy 17%).
// Round-15: 4-deep x-prefetch ring SPILLED because __launch_bounds__(256,4)
// capped VGPRs (~64) below the ring's need (~120) -> 2.2GB scratch traffic,
// 924us. Fix: __launch_bounds__(256) with NO min-wave cap; ring kept.
//
// Pipeline (3 kernels):
//   1) zero_cnt (tiny)
//   2) MEGA role-split: blocks [0,782) gemm tiles (W in LDS, x broadcast,
//      4-deep prefetch ring in named float4 regs); [782,1024) bucket fill.
//   3) gather (round-10 best): wave/node, tiered 8/4 loads, block=128.
//
// NOTE: "fillBufferAligned 256MB" rows = HARNESS d_ws poisoning, not timed.
// NOTE: coop launch silently fails (r9); NT hints +13us (r8); launch ~5us;
// VGPR caps + big live sets => scratch spill (r15); arrays => spill (r3).
//
// ws: [cnt: N int][y: N*64 ushort(bf16)][bucket: N*64 int]

#define IN_CH 128
#define OUT_CH 64
#define CAP 64
#define NPB 64
#define GEMM_BLOCKS 782   // ceil(50000/64)
#define BUCKET_BLOCKS 242
#define TOTAL_BLOCKS (GEMM_BLOCKS + BUCKET_BLOCKS)

__global__ void zero_cnt_kernel(int* __restrict__ cnt, int n) {
    int i = blockIdx.x * blockDim.x + threadIdx.x;
    if (i < n) cnt[i] = 0;
}

__device__ __forceinline__ unsigned short f2bf(float f) {
    unsigned int u = __float_as_uint(f);
    unsigned int r = (u + 0x7fffu + ((u >> 16) & 1u)) >> 16;  // RTN-even
    return (unsigned short)r;
}

#define FMA4(A, xs, Wv) \
    A.x = fmaf(xs, Wv.x, A.x); A.y = fmaf(xs, Wv.y, A.y); \
    A.z = fmaf(xs, Wv.z, A.z); A.w = fmaf(xs, Wv.w, A.w);

// load one X set (4 node rows, k4-th float4 each)
#define LOADSET(V0, V1, V2, V3, K) \
    V0 = xr0[K]; V1 = xr1[K]; V2 = xr2[K]; V3 = xr3[K];

// consume one X set against the W column-block for k4=K
#define STEPW(V0, V1, V2, V3, K) { \
    const float4 W0 = *reinterpret_cast<const float4*>(&wl[((K) * 4 + 0) * OUT_CH + c0]); \
    const float4 W1 = *reinterpret_cast<const float4*>(&wl[((K) * 4 + 1) * OUT_CH + c0]); \
    const float4 W2 = *reinterpret_cast<const float4*>(&wl[((K) * 4 + 2) * OUT_CH + c0]); \
    const float4 W3 = *reinterpret_cast<const float4*>(&wl[((K) * 4 + 3) * OUT_CH + c0]); \
    FMA4(A0, V0.x, W0) FMA4(A0, V0.y, W1) FMA4(A0, V0.z, W2) FMA4(A0, V0.w, W3) \
    FMA4(A1, V1.x, W0) FMA4(A1, V1.y, W1) FMA4(A1, V1.z, W2) FMA4(A1, V1.w, W3) \
    FMA4(A2, V2.x, W0) FMA4(A2, V2.y, W1) FMA4(A2, V2.z, W2) FMA4(A2, V2.w, W3) \
    FMA4(A3, V3.x, W0) FMA4(A3, V3.y, W1) FMA4(A3, V3.z, W2) FMA4(A3, V3.w, W3) \
}

// one pipeline group: consume k4=4g..4g+3 while loading k4=4g+4..4g+7
#define GROUP(g) \
    STEPW(XA0, XA1, XA2, XA3, 4 * (g) + 0) LOADSET(XA0, XA1, XA2, XA3, 4 * (g) + 4) \
    STEPW(XB0, XB1, XB2, XB3, 4 * (g) + 1) LOADSET(XB0, XB1, XB2, XB3, 4 * (g) + 5) \
    STEPW(XC0, XC1, XC2, XC3, 4 * (g) + 2) LOADSET(XC0, XC1, XC2, XC3, 4 * (g) + 6) \
    STEPW(XD0, XD1, XD2, XD3, 4 * (g) + 3) LOADSET(XD0, XD1, XD2, XD3, 4 * (g) + 7)

__global__ __launch_bounds__(256) void mega_kernel(const float* __restrict__ x,
                                                   const float* __restrict__ w,
                                                   const int* __restrict__ ei,
                                                   unsigned short* __restrict__ y,
                                                   int* __restrict__ cnt,
                                                   int* __restrict__ bucket,
                                                   int n, int nE) {
    __shared__ float wl[IN_CH * OUT_CH];   // 32 KB (gemm role only)
    const int t = threadIdx.x;

    if (blockIdx.x >= GEMM_BLOCKS) {
        // ---- bucket role: grid-stride over edge pairs ----
        const int nPairs = (nE + 1) / 2;
        const int stride = BUCKET_BLOCKS * 256;
        for (int p = (blockIdx.x - GEMM_BLOCKS) * 256 + t; p < nPairs; p += stride) {
            int e0 = p * 2;
            int2 s2 = reinterpret_cast<const int2*>(ei)[p];
            int2 d2 = reinterpret_cast<const int2*>(ei + nE)[p];
            int pos0 = atomicAdd(&cnt[d2.x], 1);
            if (pos0 < CAP) bucket[(size_t)d2.x * CAP + pos0] = s2.x;
            if (e0 + 1 < nE) {
                int pos1 = atomicAdd(&cnt[d2.y], 1);
                if (pos1 < CAP) bucket[(size_t)d2.y * CAP + pos1] = s2.y;
            }
        }
        return;
    }

    // ---- gemm role ----
    const int base = blockIdx.x * NPB;
    {
        const float4* w4 = reinterpret_cast<const float4*>(w);
        float4* wl4 = reinterpret_cast<float4*>(wl);
        #pragma unroll
        for (int i = 0; i < 8; ++i) wl4[t + i * 256] = w4[t + i * 256];
    }
    __syncthreads();

    const int nq = t >> 4;
    const int cq = t & 15;
    const int n0 = base + nq * 4;
    const int c0 = cq * 4;

    const float4* xr0 = reinterpret_cast<const float4*>(x + (size_t)min(n0 + 0, n - 1) * IN_CH);
    const float4* xr1 = reinterpret_cast<const float4*>(x + (size_t)min(n0 + 1, n - 1) * IN_CH);
    const float4* xr2 = reinterpret_cast<const float4*>(x + (size_t)min(n0 + 2, n - 1) * IN_CH);
    const float4* xr3 = reinterpret_cast<const float4*>(x + (size_t)min(n0 + 3, n - 1) * IN_CH);

    float4 A0 = make_float4(0.f, 0.f, 0.f, 0.f);
    float4 A1 = A0, A2 = A0, A3 = A0;

    // prefetch ring: 4 named sets (64 VGPRs), no address-taken arrays
    float4 XA0, XA1, XA2, XA3, XB0, XB1, XB2, XB3;
    float4 XC0, XC1, XC2, XC3, XD0, XD1, XD2, XD3;

    LOADSET(XA0, XA1, XA2, XA3, 0)
    LOADSET(XB0, XB1, XB2, XB3, 1)
    LOADSET(XC0, XC1, XC2, XC3, 2)
    LOADSET(XD0, XD1, XD2, XD3, 3)
    GROUP(0) GROUP(1) GROUP(2) GROUP(3) GROUP(4) GROUP(5) GROUP(6)
    STEPW(XA0, XA1, XA2, XA3, 28)
    STEPW(XB0, XB1, XB2, XB3, 29)
    STEPW(XC0, XC1, XC2, XC3, 30)
    STEPW(XD0, XD1, XD2, XD3, 31)

    #define STORE_ROW(J, A)                                                            \
        if (n0 + J < n) {                                                              \
            uint2 pk;                                                                  \
            pk.x = (unsigned int)f2bf(A.x) | ((unsigned int)f2bf(A.y) << 16);          \
            pk.y = (unsigned int)f2bf(A.z) | ((unsigned int)f2bf(A.w) << 16);          \
            *reinterpret_cast<uint2*>(&y[(size_t)(n0 + J) * OUT_CH + c0]) = pk;        \
        }
    STORE_ROW(0, A0)
    STORE_ROW(1, A1)
    STORE_ROW(2, A2)
    STORE_ROW(3, A3)
    #undef STORE_ROW
}

// Gather (round-10 best): one wave per node, block=128 (32 waves/CU).
#define EDGE_FMA(c, v) \
    ax = fmaf(c, __uint_as_float((v) << 16), ax); \
    ay = fmaf(c, __uint_as_float((v) & 0xffff0000u), ay);

__global__ __launch_bounds__(128) void gather_kernel(const int* __restrict__ cnt,
                                                     const int* __restrict__ bucket,
                                                     const unsigned short* __restrict__ y,
                                                     const float* __restrict__ bias,
                                                     float* __restrict__ out, int n) {
    const int wid  = threadIdx.x >> 6;
    const int lane = threadIdx.x & 63;
    const int nid  = blockIdx.x * 2 + wid;
    if (nid >= n) return;
    const int hw = lane >> 5;
    const int cp = lane & 31;

    int deg = cnt[nid];
    if (deg > CAP) deg = CAP;
    const float isd_d = rsqrtf((float)cnt[nid] + 1.0f);

    int   s_l  = 0;
    float cf_l = 0.f;
    if (lane < deg) {
        s_l  = bucket[(size_t)nid * CAP + lane];
        cf_l = isd_d * rsqrtf((float)cnt[s_l] + 1.0f);
    }

    float ax = 0.f, ay = 0.f;
    if (hw == 0) {
        float2 b2 = reinterpret_cast<const float2*>(bias)[cp];
        unsigned int u = reinterpret_cast<const unsigned int*>(y + (size_t)nid * OUT_CH)[cp];
        float sl = isd_d * isd_d;
        ax = fmaf(sl, __uint_as_float(u << 16), b2.x);
        ay = fmaf(sl, __uint_as_float(u & 0xffff0000u), b2.y);
    }

    for (int k = 0; k < deg; k += 16) {
        int rem = deg - k;
        if (rem > 8) {
            int s0 = __shfl(s_l, k + 0 + hw),  s1 = __shfl(s_l, k + 2 + hw);
            int s2 = __shfl(s_l, k + 4 + hw),  s3 = __shfl(s_l, k + 6 + hw);
            int s4 = __shfl(s_l, k + 8 + hw),  s5 = __shfl(s_l, k + 10 + hw);
            int s6 = __shfl(s_l, k + 12 + hw), s7 = __shfl(s_l, k + 14 + hw);
            unsigned int v0 = reinterpret_cast<const unsigned int*>(y + (size_t)s0 * OUT_CH)[cp];
            unsigned int v1 = reinterpret_cast<const unsigned int*>(y + (size_t)s1 * OUT_CH)[cp];
            unsigned int v2 = reinterpret_cast<const unsigned int*>(y + (size_t)s2 * OUT_CH)[cp];
            unsigned int v3 = reinterpret_cast<const unsigned int*>(y + (size_t)s3 * OUT_CH)[cp];
            unsigned int v4 = reinterpret_cast<const unsigned int*>(y + (size_t)s4 * OUT_CH)[cp];
            unsigned int v5 = reinterpret_cast<const unsigned int*>(y + (size_t)s5 * OUT_CH)[cp];
            unsigned int v6 = reinterpret_cast<const unsigned int*>(y + (size_t)s6 * OUT_CH)[cp];
            unsigned int v7 = reinterpret_cast<const unsigned int*>(y + (size_t)s7 * OUT_CH)[cp];
            float c0 = __shfl(cf_l, k + 0 + hw),  c1 = __shfl(cf_l, k + 2 + hw);
            float c2 = __shfl(cf_l, k + 4 + hw),  c3 = __shfl(cf_l, k + 6 + hw);
            float c4 = __shfl(cf_l, k + 8 + hw),  c5 = __shfl(cf_l, k + 10 + hw);
            float c6 = __shfl(cf_l, k + 12 + hw), c7 = __shfl(cf_l, k + 14 + hw);
            EDGE_FMA(c0, v0) EDGE_FMA(c1, v1) EDGE_FMA(c2, v2) EDGE_FMA(c3, v3)
            EDGE_FMA(c4, v4) EDGE_FMA(c5, v5) EDGE_FMA(c6, v6) EDGE_FMA(c7, v7)
        } else {
            int s0 = __shfl(s_l, k + 0 + hw), s1 = __shfl(s_l, k + 2 + hw);
            int s2 = __shfl(s_l, k + 4 + hw), s3 = __shfl(s_l, k + 6 + hw);
            unsigned int v0 = reinterpret_cast<const unsigned int*>(y + (size_t)s0 * OUT_CH)[cp];
            unsigned int v1 = reinterpret_cast<const unsigned int*>(y + (size_t)s1 * OUT_CH)[cp];
            unsigned int v2 = reinterpret_cast<const unsigned int*>(y + (size_t)s2 * OUT_CH)[cp];
            unsigned int v3 = reinterpret_cast<const unsigned int*>(y + (size_t)s3 * OUT_CH)[cp];
            float c0 = __shfl(cf_l, k + 0 + hw), c1 = __shfl(cf_l, k + 2 + hw);
            float c2 = __shfl(cf_l, k + 4 + hw), c3 = __shfl(cf_l, k + 6 + hw);
            EDGE_FMA(c0, v0) EDGE_FMA(c1, v1) EDGE_FMA(c2, v2) EDGE_FMA(c3, v3)
        }
    }

    ax += __shfl_xor(ax, 32);
    ay += __shfl_xor(ay, 32);
    if (hw == 0) {
        float2 o; o.x = ax; o.y = ay;
        reinterpret_cast<float2*>(out + (size_t)nid * OUT_CH)[cp] = o;
    }
}

extern "C" void kernel_launch(void* const* d_in, const int* in_sizes, int n_in,
                              void* d_out, int out_size, void* d_ws, size_t ws_size,
                              hipStream_t stream) {
    const float* x    = (const float*)d_in[0];
    const int*   ei   = (const int*)d_in[1];
    const float* w    = (const float*)d_in[2];
    const float* bias = (const float*)d_in[3];
    float* out = (float*)d_out;

    const int n  = in_sizes[0] / IN_CH;   // 50000
    const int nE = in_sizes[1] / 2;       // 600000

    char* p = (char*)d_ws;
    auto align256 = [](size_t v) { return (v + 255) & ~(size_t)255; };
    int*            cnt    = (int*)p;             p += align256((size_t)n * 4);
    unsigned short* y      = (unsigned short*)p;  p += align256((size_t)n * OUT_CH * 2);
    int*            bucket = (int*)p;

    zero_cnt_kernel<<<(n + 255) / 256, 256, 0, stream>>>(cnt, n);
    mega_kernel<<<TOTAL_BLOCKS, 256, 0, stream>>>(x, w, ei, y, cnt, bucket, n, nE);
    gather_kernel<<<(n + 1) / 2, 128, 0, stream>>>(cnt, bucket, y, bias, out, n);
}

// Round 17
// 90.083 us; speedup vs baseline: 10.4346x; 5.2224x over previous
//
#include <hip/hip_runtime.h>
#include <hip/hip_bf16.h>

// GCN layer: out = A_hat @ (x @ W) + bias,  A_hat = D^-1/2 (A+I) D^-1/2.
// N=50000, E=600000, IN=128, OUT=64.
//
// r13: gemm 45us, latency-bound (VALUBusy 17%, occupancy 32%: grid=4/CU and
// 32KB LDS cap). r15/r16: hand prefetch rings spill (compiler hoists loads,
// live-set explodes) - source pipelining abandoned for good.
// r17 fix: NO LDS in gemm. W read straight from global: for fixed kk the
// wave's 16 cq lanes read 16 consecutive float4 = ONE coalesced 256B txn,
// and W (32KB) stays L1/L2-resident. Tiles shrink to NPB=32 -> 1563 gemm
// blocks, no syncthreads, VGPR ~40 -> occupancy way up; 6 independent
// loads/thread/k4 give the compiler natural MLP.
//
// Pipeline (3 kernels):
//   1) zero_cnt (tiny)
//   2) MEGA role-split: [0,1563) gemm tiles; [1563,1813) bucket grid-stride.
//   3) gather (round-10 best): wave/node, tiered 8/4 loads, block=128.
//
// NOTE: "fillBufferAligned 256MB" rows = HARNESS d_ws poisoning, not timed.
// NOTE: coop launch fails silently (r9); NT hints +13us (r8); VGPR caps or
// hand-unrolled rings => scratch spill (r3/r15/r16).
//
// ws: [cnt: N int][y: N*64 ushort(bf16)][bucket: N*64 int]

#define IN_CH 128
#define OUT_CH 64
#define CAP 64
#define NPB 32                 // nodes per gemm block (thread = 2 nodes x 4 ch)
#define GEMM_BLOCKS 1563       // ceil(50000/32)
#define BUCKET_BLOCKS 250
#define TOTAL_BLOCKS (GEMM_BLOCKS + BUCKET_BLOCKS)

__global__ void zero_cnt_kernel(int* __restrict__ cnt, int n) {
    int i = blockIdx.x * blockDim.x + threadIdx.x;
    if (i < n) cnt[i] = 0;
}

__device__ __forceinline__ unsigned short f2bf(float f) {
    unsigned int u = __float_as_uint(f);
    unsigned int r = (u + 0x7fffu + ((u >> 16) & 1u)) >> 16;  // RTN-even
    return (unsigned short)r;
}

#define FMA4(A, xs, Wv) \
    A.x = fmaf(xs, Wv.x, A.x); A.y = fmaf(xs, Wv.y, A.y); \
    A.z = fmaf(xs, Wv.z, A.z); A.w = fmaf(xs, Wv.w, A.w);

__global__ __launch_bounds__(256) void mega_kernel(const float* __restrict__ x,
                                                   const float* __restrict__ w,
                                                   const int* __restrict__ ei,
                                                   unsigned short* __restrict__ y,
                                                   int* __restrict__ cnt,
                                                   int* __restrict__ bucket,
                                                   int n, int nE) {
    const int t = threadIdx.x;

    if (blockIdx.x >= GEMM_BLOCKS) {
        // ---- bucket role: grid-stride over edge pairs ----
        const int nPairs = (nE + 1) / 2;
        const int stride = BUCKET_BLOCKS * 256;
        for (int p = (blockIdx.x - GEMM_BLOCKS) * 256 + t; p < nPairs; p += stride) {
            int e0 = p * 2;
            int2 s2 = reinterpret_cast<const int2*>(ei)[p];
            int2 d2 = reinterpret_cast<const int2*>(ei + nE)[p];
            int pos0 = atomicAdd(&cnt[d2.x], 1);
            if (pos0 < CAP) bucket[(size_t)d2.x * CAP + pos0] = s2.x;
            if (e0 + 1 < nE) {
                int pos1 = atomicAdd(&cnt[d2.y], 1);
                if (pos1 < CAP) bucket[(size_t)d2.y * CAP + pos1] = s2.y;
            }
        }
        return;
    }

    // ---- gemm role: 32 nodes/block, thread = 2 nodes x 4 channels ----
    const int base = blockIdx.x * NPB;
    const int nq = t >> 4;          // 0..15
    const int cq = t & 15;          // 0..15
    const int n0 = base + nq * 2;   // this thread's 2 node rows
    const int c0 = cq * 4;

    const float4* xr0 = reinterpret_cast<const float4*>(x + (size_t)min(n0 + 0, n - 1) * IN_CH);
    const float4* xr1 = reinterpret_cast<const float4*>(x + (size_t)min(n0 + 1, n - 1) * IN_CH);
    const float4* w4  = reinterpret_cast<const float4*>(w);   // w[k][64] -> idx k*16+cq

    float4 A0 = make_float4(0.f, 0.f, 0.f, 0.f);
    float4 A1 = A0;

    #pragma unroll 8
    for (int k4 = 0; k4 < IN_CH / 4; ++k4) {
        const float4 X0 = xr0[k4];
        const float4 X1 = xr1[k4];
        const float4 W0 = w4[(k4 * 4 + 0) * 16 + cq];   // coalesced 256B across cq
        const float4 W1 = w4[(k4 * 4 + 1) * 16 + cq];
        const float4 W2 = w4[(k4 * 4 + 2) * 16 + cq];
        const float4 W3 = w4[(k4 * 4 + 3) * 16 + cq];
        FMA4(A0, X0.x, W0) FMA4(A0, X0.y, W1) FMA4(A0, X0.z, W2) FMA4(A0, X0.w, W3)
        FMA4(A1, X1.x, W0) FMA4(A1, X1.y, W1) FMA4(A1, X1.z, W2) FMA4(A1, X1.w, W3)
    }

    #define STORE_ROW(J, A)                                                            \
        if (n0 + J < n) {                                                              \
            uint2 pk;                                                                  \
            pk.x = (unsigned int)f2bf(A.x) | ((unsigned int)f2bf(A.y) << 16);          \
            pk.y = (unsigned int)f2bf(A.z) | ((unsigned int)f2bf(A.w) << 16);          \
            *reinterpret_cast<uint2*>(&y[(size_t)(n0 + J) * OUT_CH + c0]) = pk;        \
        }
    STORE_ROW(0, A0)
    STORE_ROW(1, A1)
    #undef STORE_ROW
}

// Gather (round-10 best): one wave per node, block=128 (32 waves/CU).
#define EDGE_FMA(c, v) \
    ax = fmaf(c, __uint_as_float((v) << 16), ax); \
    ay = fmaf(c, __uint_as_float((v) & 0xffff0000u), ay);

__global__ __launch_bounds__(128) void gather_kernel(const int* __restrict__ cnt,
                                                     const int* __restrict__ bucket,
                                                     const unsigned short* __restrict__ y,
                                                     const float* __restrict__ bias,
                                                     float* __restrict__ out, int n) {
    const int wid  = threadIdx.x >> 6;
    const int lane = threadIdx.x & 63;
    const int nid  = blockIdx.x * 2 + wid;
    if (nid >= n) return;
    const int hw = lane >> 5;
    const int cp = lane & 31;

    int deg = cnt[nid];
    if (deg > CAP) deg = CAP;
    const float isd_d = rsqrtf((float)cnt[nid] + 1.0f);

    int   s_l  = 0;
    float cf_l = 0.f;
    if (lane < deg) {
        s_l  = bucket[(size_t)nid * CAP + lane];
        cf_l = isd_d * rsqrtf((float)cnt[s_l] + 1.0f);
    }

    float ax = 0.f, ay = 0.f;
    if (hw == 0) {
        float2 b2 = reinterpret_cast<const float2*>(bias)[cp];
        unsigned int u = reinterpret_cast<const unsigned int*>(y + (size_t)nid * OUT_CH)[cp];
        float sl = isd_d * isd_d;
        ax = fmaf(sl, __uint_as_float(u << 16), b2.x);
        ay = fmaf(sl, __uint_as_float(u & 0xffff0000u), b2.y);
    }

    for (int k = 0; k < deg; k += 16) {
        int rem = deg - k;
        if (rem > 8) {
            int s0 = __shfl(s_l, k + 0 + hw),  s1 = __shfl(s_l, k + 2 + hw);
            int s2 = __shfl(s_l, k + 4 + hw),  s3 = __shfl(s_l, k + 6 + hw);
            int s4 = __shfl(s_l, k + 8 + hw),  s5 = __shfl(s_l, k + 10 + hw);
            int s6 = __shfl(s_l, k + 12 + hw), s7 = __shfl(s_l, k + 14 + hw);
            unsigned int v0 = reinterpret_cast<const unsigned int*>(y + (size_t)s0 * OUT_CH)[cp];
            unsigned int v1 = reinterpret_cast<const unsigned int*>(y + (size_t)s1 * OUT_CH)[cp];
            unsigned int v2 = reinterpret_cast<const unsigned int*>(y + (size_t)s2 * OUT_CH)[cp];
            unsigned int v3 = reinterpret_cast<const unsigned int*>(y + (size_t)s3 * OUT_CH)[cp];
            unsigned int v4 = reinterpret_cast<const unsigned int*>(y + (size_t)s4 * OUT_CH)[cp];
            unsigned int v5 = reinterpret_cast<const unsigned int*>(y + (size_t)s5 * OUT_CH)[cp];
            unsigned int v6 = reinterpret_cast<const unsigned int*>(y + (size_t)s6 * OUT_CH)[cp];
            unsigned int v7 = reinterpret_cast<const unsigned int*>(y + (size_t)s7 * OUT_CH)[cp];
            float c0 = __shfl(cf_l, k + 0 + hw),  c1 = __shfl(cf_l, k + 2 + hw);
            float c2 = __shfl(cf_l, k + 4 + hw),  c3 = __shfl(cf_l, k + 6 + hw);
            float c4 = __shfl(cf_l, k + 8 + hw),  c5 = __shfl(cf_l, k + 10 + hw);
            float c6 = __shfl(cf_l, k + 12 + hw), c7 = __shfl(cf_l, k + 14 + hw);
            EDGE_FMA(c0, v0) EDGE_FMA(c1, v1) EDGE_FMA(c2, v2) EDGE_FMA(c3, v3)
            EDGE_FMA(c4, v4) EDGE_FMA(c5, v5) EDGE_FMA(c6, v6) EDGE_FMA(c7, v7)
        } else {
            int s0 = __shfl(s_l, k + 0 + hw), s1 = __shfl(s_l, k + 2 + hw);
            int s2 = __shfl(s_l, k + 4 + hw), s3 = __shfl(s_l, k + 6 + hw);
            unsigned int v0 = reinterpret_cast<const unsigned int*>(y + (size_t)s0 * OUT_CH)[cp];
            unsigned int v1 = reinterpret_cast<const unsigned int*>(y + (size_t)s1 * OUT_CH)[cp];
            unsigned int v2 = reinterpret_cast<const unsigned int*>(y + (size_t)s2 * OUT_CH)[cp];
            unsigned int v3 = reinterpret_cast<const unsigned int*>(y + (size_t)s3 * OUT_CH)[cp];
            float c0 = __shfl(cf_l, k + 0 + hw), c1 = __shfl(cf_l, k + 2 + hw);
            float c2 = __shfl(cf_l, k + 4 + hw), c3 = __shfl(cf_l, k + 6 + hw);
            EDGE_FMA(c0, v0) EDGE_FMA(c1, v1) EDGE_FMA(c2, v2) EDGE_FMA(c3, v3)
        }
    }

    ax += __shfl_xor(ax, 32);
    ay += __shfl_xor(ay, 32);
    if (hw == 0) {
        float2 o; o.x = ax; o.y = ay;
        reinterpret_cast<float2*>(out + (size_t)nid * OUT_CH)[cp] = o;
    }
}

extern "C" void kernel_launch(void* const* d_in, const int* in_sizes, int n_in,
                              void* d_out, int out_size, void* d_ws, size_t ws_size,
                              hipStream_t stream) {
    const float* x    = (const float*)d_in[0];
    const int*   ei   = (const int*)d_in[1];
    const float* w    = (const float*)d_in[2];
    const float* bias = (const float*)d_in[3];
    float* out = (float*)d_out;

    const int n  = in_sizes[0] / IN_CH;   // 50000
    const int nE = in_sizes[1] / 2;       // 600000

    char* p = (char*)d_ws;
    auto align256 = [](size_t v) { return (v + 255) & ~(size_t)255; };
    int*            cnt    = (int*)p;             p += align256((size_t)n * 4);
    unsigned short* y      = (unsigned short*)p;  p += align256((size_t)n * OUT_CH * 2);
    int*            bucket = (int*)p;

    zero_cnt_kernel<<<(n + 255) / 256, 256, 0, stream>>>(cnt, n);
    mega_kernel<<<TOTAL_BLOCKS, 256, 0, stream>>>(x, w, ei, y, cnt, bucket, n, nE);
    gather_kernel<<<(n + 1) / 2, 128, 0, stream>>>(cnt, bucket, y, bias, out, n);
}

// Round 18
// 73.417 us; speedup vs baseline: 12.8033x; 1.2270x over previous
//
#include <hip/hip_runtime.h>
#include <hip/hip_bf16.h>

// GCN layer: out = A_hat @ (x @ W) + bias,  A_hat = D^-1/2 (A+I) D^-1/2.
// N=50000, E=600000, IN=128, OUT=64.
//
// GEMM history: r13 W-in-LDS/x-broadcast = 45us (latency, x loads serialized);
// r15/r16 manual prefetch rings = scratch spill (2.2GB/1GB); r17 no-LDS =
// 71us (vmem instruction count: 192 loads/thread through L1).
// r18: textbook tile - BOTH X and W staged in LDS (coalesced, few vmem
// instrs), inner loop pure ds_read_b128 (8 reads -> 64 FMA per k4), named
// float4 regs only. X tile XOR-swizzled (c4 ^= row&7, both write+read) to
// kill the stride-128 4-way bank conflict of round 3. LDS = exactly 64KB.
//
// Pipeline (3 kernels):
//   1) zero_cnt (must precede bucket atomics; no cross-block order in mega)
//   2) MEGA role-split: [0,782) gemm tiles; [782,1024) bucket grid-stride.
//   3) gather (r10 best): wave/node, tiered 8/4 loads in flight, block=128.
//
// NOTE: "fillBufferAligned 256MB" profile rows = HARNESS d_ws poisoning.
// NOTE: coop launch fails silently (r9); NT hints +13us (r8); VGPR caps or
// hand-unrolled rings => scratch spill (r3/r15/r16).
//
// ws: [cnt: N int][y: N*64 ushort(bf16)][bucket: N*64 int]

#define IN_CH 128
#define OUT_CH 64
#define CAP 64
#define NPB 64
#define GEMM_BLOCKS 782   // ceil(50000/64)
#define BUCKET_BLOCKS 242
#define TOTAL_BLOCKS (GEMM_BLOCKS + BUCKET_BLOCKS)

__global__ void zero_cnt_kernel(int* __restrict__ cnt, int n) {
    int i = blockIdx.x * blockDim.x + threadIdx.x;
    if (i < n) cnt[i] = 0;
}

__device__ __forceinline__ unsigned short f2bf(float f) {
    unsigned int u = __float_as_uint(f);
    unsigned int r = (u + 0x7fffu + ((u >> 16) & 1u)) >> 16;  // RTN-even
    return (unsigned short)r;
}

#define FMA4(A, xs, Wv) \
    A.x = fmaf(xs, Wv.x, A.x); A.y = fmaf(xs, Wv.y, A.y); \
    A.z = fmaf(xs, Wv.z, A.z); A.w = fmaf(xs, Wv.w, A.w);

__global__ __launch_bounds__(256) void mega_kernel(const float* __restrict__ x,
                                                   const float* __restrict__ w,
                                                   const int* __restrict__ ei,
                                                   unsigned short* __restrict__ y,
                                                   int* __restrict__ cnt,
                                                   int* __restrict__ bucket,
                                                   int n, int nE) {
    // 64KB LDS: W tile (32KB) + X tile (32KB, XOR-swizzled by row&7)
    __shared__ float wl[IN_CH * OUT_CH];
    __shared__ float xl[NPB * IN_CH];
    const int t = threadIdx.x;

    if (blockIdx.x >= GEMM_BLOCKS) {
        // ---- bucket role: grid-stride over edge pairs ----
        const int nPairs = (nE + 1) / 2;
        const int stride = BUCKET_BLOCKS * 256;
        for (int p = (blockIdx.x - GEMM_BLOCKS) * 256 + t; p < nPairs; p += stride) {
            int e0 = p * 2;
            int2 s2 = reinterpret_cast<const int2*>(ei)[p];
            int2 d2 = reinterpret_cast<const int2*>(ei + nE)[p];
            int pos0 = atomicAdd(&cnt[d2.x], 1);
            if (pos0 < CAP) bucket[(size_t)d2.x * CAP + pos0] = s2.x;
            if (e0 + 1 < nE) {
                int pos1 = atomicAdd(&cnt[d2.y], 1);
                if (pos1 < CAP) bucket[(size_t)d2.y * CAP + pos1] = s2.y;
            }
        }
        return;
    }

    // ---- gemm role: 64 nodes/block, thread = 4 nodes x 4 channels ----
    const int base = blockIdx.x * NPB;
    {   // stage W (coalesced float4)
        const float4* w4 = reinterpret_cast<const float4*>(w);
        float4* wl4 = reinterpret_cast<float4*>(wl);
        #pragma unroll
        for (int i = 0; i < 8; ++i) wl4[t + i * 256] = w4[t + i * 256];
    }
    {   // stage X tile (coalesced float4), XOR-swizzle c4 ^= row&7, OOB -> 0
        const float4* xg = reinterpret_cast<const float4*>(x) + (size_t)base * 32;
        float4* xl4 = reinterpret_cast<float4*>(xl);
        const int rows_ok = min(NPB, n - base);
        #pragma unroll
        for (int r = 0; r < 8; ++r) {
            int idx = t + r * 256;          // 0..2047
            int row = idx >> 5;             // 0..63
            int c4  = idx & 31;             // float4 column 0..31
            float4 v = make_float4(0.f, 0.f, 0.f, 0.f);
            if (row < rows_ok) v = xg[idx];
            xl4[row * 32 + (c4 ^ (row & 7))] = v;
        }
    }
    __syncthreads();

    const int nq = t >> 4;          // 0..15 -> 4 block-local rows
    const int cq = t & 15;          // 0..15 -> 4 channels
    const int r0 = nq * 4;
    const int c0 = cq * 4;

    const float4* xl4 = reinterpret_cast<const float4*>(xl);
    const float4* wl4 = reinterpret_cast<const float4*>(wl);

    float4 A0 = make_float4(0.f, 0.f, 0.f, 0.f);
    float4 A1 = A0, A2 = A0, A3 = A0;

    #pragma unroll 4
    for (int k4 = 0; k4 < IN_CH / 4; ++k4) {
        const float4 X0 = xl4[(r0 + 0) * 32 + (k4 ^ ((r0 + 0) & 7))];
        const float4 X1 = xl4[(r0 + 1) * 32 + (k4 ^ ((r0 + 1) & 7))];
        const float4 X2 = xl4[(r0 + 2) * 32 + (k4 ^ ((r0 + 2) & 7))];
        const float4 X3 = xl4[(r0 + 3) * 32 + (k4 ^ ((r0 + 3) & 7))];
        const float4 W0 = wl4[(k4 * 4 + 0) * 16 + cq];
        const float4 W1 = wl4[(k4 * 4 + 1) * 16 + cq];
        const float4 W2 = wl4[(k4 * 4 + 2) * 16 + cq];
        const float4 W3 = wl4[(k4 * 4 + 3) * 16 + cq];
        FMA4(A0, X0.x, W0) FMA4(A0, X0.y, W1) FMA4(A0, X0.z, W2) FMA4(A0, X0.w, W3)
        FMA4(A1, X1.x, W0) FMA4(A1, X1.y, W1) FMA4(A1, X1.z, W2) FMA4(A1, X1.w, W3)
        FMA4(A2, X2.x, W0) FMA4(A2, X2.y, W1) FMA4(A2, X2.z, W2) FMA4(A2, X2.w, W3)
        FMA4(A3, X3.x, W0) FMA4(A3, X3.y, W1) FMA4(A3, X3.z, W2) FMA4(A3, X3.w, W3)
    }

    #define STORE_ROW(J, A)                                                            \
        if (base + r0 + J < n) {                                                       \
            uint2 pk;                                                                  \
            pk.x = (unsigned int)f2bf(A.x) | ((unsigned int)f2bf(A.y) << 16);          \
            pk.y = (unsigned int)f2bf(A.z) | ((unsigned int)f2bf(A.w) << 16);          \
            *reinterpret_cast<uint2*>(&y[(size_t)(base + r0 + J) * OUT_CH + c0]) = pk; \
        }
    STORE_ROW(0, A0)
    STORE_ROW(1, A1)
    STORE_ROW(2, A2)
    STORE_ROW(3, A3)
    #undef STORE_ROW
}

// Gather (round-10 best): one wave per node, block=128 (32 waves/CU).
#define EDGE_FMA(c, v) \
    ax = fmaf(c, __uint_as_float((v) << 16), ax); \
    ay = fmaf(c, __uint_as_float((v) & 0xffff0000u), ay);

__global__ __launch_bounds__(128) void gather_kernel(const int* __restrict__ cnt,
                                                     const int* __restrict__ bucket,
                                                     const unsigned short* __restrict__ y,
                                                     const float* __restrict__ bias,
                                                     float* __restrict__ out, int n) {
    const int wid  = threadIdx.x >> 6;
    const int lane = threadIdx.x & 63;
    const int nid  = blockIdx.x * 2 + wid;
    if (nid >= n) return;
    const int hw = lane >> 5;
    const int cp = lane & 31;

    int deg = cnt[nid];
    if (deg > CAP) deg = CAP;
    const float isd_d = rsqrtf((float)cnt[nid] + 1.0f);

    int   s_l  = 0;
    float cf_l = 0.f;
    if (lane < deg) {
        s_l  = bucket[(size_t)nid * CAP + lane];
        cf_l = isd_d * rsqrtf((float)cnt[s_l] + 1.0f);
    }

    float ax = 0.f, ay = 0.f;
    if (hw == 0) {
        float2 b2 = reinterpret_cast<const float2*>(bias)[cp];
        unsigned int u = reinterpret_cast<const unsigned int*>(y + (size_t)nid * OUT_CH)[cp];
        float sl = isd_d * isd_d;
        ax = fmaf(sl, __uint_as_float(u << 16), b2.x);
        ay = fmaf(sl, __uint_as_float(u & 0xffff0000u), b2.y);
    }

    for (int k = 0; k < deg; k += 16) {
        int rem = deg - k;
        if (rem > 8) {
            int s0 = __shfl(s_l, k + 0 + hw),  s1 = __shfl(s_l, k + 2 + hw);
            int s2 = __shfl(s_l, k + 4 + hw),  s3 = __shfl(s_l, k + 6 + hw);
            int s4 = __shfl(s_l, k + 8 + hw),  s5 = __shfl(s_l, k + 10 + hw);
            int s6 = __shfl(s_l, k + 12 + hw), s7 = __shfl(s_l, k + 14 + hw);
            unsigned int v0 = reinterpret_cast<const unsigned int*>(y + (size_t)s0 * OUT_CH)[cp];
            unsigned int v1 = reinterpret_cast<const unsigned int*>(y + (size_t)s1 * OUT_CH)[cp];
            unsigned int v2 = reinterpret_cast<const unsigned int*>(y + (size_t)s2 * OUT_CH)[cp];
            unsigned int v3 = reinterpret_cast<const unsigned int*>(y + (size_t)s3 * OUT_CH)[cp];
            unsigned int v4 = reinterpret_cast<const unsigned int*>(y + (size_t)s4 * OUT_CH)[cp];
            unsigned int v5 = reinterpret_cast<const unsigned int*>(y + (size_t)s5 * OUT_CH)[cp];
            unsigned int v6 = reinterpret_cast<const unsigned int*>(y + (size_t)s6 * OUT_CH)[cp];
            unsigned int v7 = reinterpret_cast<const unsigned int*>(y + (size_t)s7 * OUT_CH)[cp];
            float c0 = __shfl(cf_l, k + 0 + hw),  c1 = __shfl(cf_l, k + 2 + hw);
            float c2 = __shfl(cf_l, k + 4 + hw),  c3 = __shfl(cf_l, k + 6 + hw);
            float c4 = __shfl(cf_l, k + 8 + hw),  c5 = __shfl(cf_l, k + 10 + hw);
            float c6 = __shfl(cf_l, k + 12 + hw), c7 = __shfl(cf_l, k + 14 + hw);
            EDGE_FMA(c0, v0) EDGE_FMA(c1, v1) EDGE_FMA(c2, v2) EDGE_FMA(c3, v3)
            EDGE_FMA(c4, v4) EDGE_FMA(c5, v5) EDGE_FMA(c6, v6) EDGE_FMA(c7, v7)
        } else {
            int s0 = __shfl(s_l, k + 0 + hw), s1 = __shfl(s_l, k + 2 + hw);
            int s2 = __shfl(s_l, k + 4 + hw), s3 = __shfl(s_l, k + 6 + hw);
            unsigned int v0 = reinterpret_cast<const unsigned int*>(y + (size_t)s0 * OUT_CH)[cp];
            unsigned int v1 = reinterpret_cast<const unsigned int*>(y + (size_t)s1 * OUT_CH)[cp];
            unsigned int v2 = reinterpret_cast<const unsigned int*>(y + (size_t)s2 * OUT_CH)[cp];
            unsigned int v3 = reinterpret_cast<const unsigned int*>(y + (size_t)s3 * OUT_CH)[cp];
            float c0 = __shfl(cf_l, k + 0 + hw), c1 = __shfl(cf_l, k + 2 + hw);
            float c2 = __shfl(cf_l, k + 4 + hw), c3 = __shfl(cf_l, k + 6 + hw);
            EDGE_FMA(c0, v0) EDGE_FMA(c1, v1) EDGE_FMA(c2, v2) EDGE_FMA(c3, v3)
        }
    }

    ax += __shfl_xor(ax, 32);
    ay += __shfl_xor(ay, 32);
    if (hw == 0) {
        float2 o; o.x = ax; o.y = ay;
        reinterpret_cast<float2*>(out + (size_t)nid * OUT_CH)[cp] = o;
    }
}

extern "C" void kernel_launch(void* const* d_in, const int* in_sizes, int n_in,
                              void* d_out, int out_size, void* d_ws, size_t ws_size,
                              hipStream_t stream) {
    const float* x    = (const float*)d_in[0];
    const int*   ei   = (const int*)d_in[1];
    const float* w    = (const float*)d_in[2];
    const float* bias = (const float*)d_in[3];
    float* out = (float*)d_out;

    const int n  = in_sizes[0] / IN_CH;   // 50000
    const int nE = in_sizes[1] / 2;       // 600000

    char* p = (char*)d_ws;
    auto align256 = [](size_t v) { return (v + 255) & ~(size_t)255; };
    int*            cnt    = (int*)p;             p += align256((size_t)n * 4);
    unsigned short* y      = (unsigned short*)p;  p += align256((size_t)n * OUT_CH * 2);
    int*            bucket = (int*)p;

    zero_cnt_kernel<<<(n + 255) / 256, 256, 0, stream>>>(cnt, n);
    mega_kernel<<<TOTAL_BLOCKS, 256, 0, stream>>>(x, w, ei, y, cnt, bucket, n, nE);
    gather_kernel<<<(n + 1) / 2, 128, 0, stream>>>(cnt, bucket, y, bias, out, n);
}